// Round 10
// baseline (123.430 us; speedup 1.0000x reference)
//
#include <hip/hip_runtime.h>

#define B 2
#define N 64
#define D 256
#define H 8
#define DK 32
#define M (B * N * N) // 8192

typedef __attribute__((ext_vector_type(8))) short bf16x8;
typedef __attribute__((ext_vector_type(4))) float f32x4;
typedef __attribute__((ext_vector_type(2))) float f32x2;

// P is head-major: 4 proj planes of [b][h][r1*64+r2][32] bf16
#define PROJ_ELEMS (2097152)  // B*H*4096*32

__device__ __forceinline__ ushort f2b(float f) {
    union { float f; unsigned u; } v; v.f = f;
    unsigned r = v.u + 0x7fffu + ((v.u >> 16) & 1u); // RNE
    return (ushort)(r >> 16);
}
__device__ __forceinline__ float b2f(ushort u) {
    union { unsigned u; float f; } v; v.u = ((unsigned)u) << 16; return v.f;
}
// unpack 2 packed bf16 (u32) -> float2
__device__ __forceinline__ f32x2 up2(unsigned u) {
    union { unsigned u; float f; } lo, hi;
    lo.u = u << 16; hi.u = u & 0xffff0000u;
    f32x2 r; r.x = lo.f; r.y = hi.f; return r;
}

// async 16B/lane global->LDS (dst = wave-uniform base + lane*16)
__device__ __forceinline__ void glds16(const ushort* g, ushort* l) {
    __builtin_amdgcn_global_load_lds(
        (const __attribute__((address_space(1))) unsigned int*)g,
        (__attribute__((address_space(3))) unsigned int*)l, 16, 0, 0);
}

// ---------------------------------------------------------------------------
// Cast (weights only, v14): 5 weights -> Wcat[1280][256] bf16; biases -> f32.
// State cast is FUSED into the proj GEMM (A consumed f32 directly).
// 320 blocks x 256 = 81920 threads, one float4 each.
// ---------------------------------------------------------------------------
__global__ __launch_bounds__(256) void cast_w(const float* __restrict__ W_lk, const float* __restrict__ W_rk,
                                              const float* __restrict__ W_lv, const float* __restrict__ W_rv,
                                              const float* __restrict__ W_o,
                                              const float* __restrict__ b_lk, const float* __restrict__ b_rk,
                                              const float* __restrict__ b_lv, const float* __restrict__ b_rv,
                                              const float* __restrict__ b_o,
                                              ushort* __restrict__ Wcat,
                                              float* __restrict__ bias_cat) {
    const int gid = blockIdx.x * 256 + threadIdx.x;   // 0..81919
    const float* Ws[5] = {W_lk, W_rk, W_lv, W_rv, W_o};
    const float* bs[5] = {b_lk, b_rk, b_lv, b_rv, b_o};

    if (gid < 1280) bias_cat[gid] = bs[gid >> 8][gid & 255];

    const int row = gid >> 6;            // 0..1279
    const int k4 = (gid & 63) * 4;
    const float* W = Ws[row >> 8];
    float4 v = *(const float4*)&W[(size_t)(row & 255) * 256 + k4];
    ushort4 o = {f2b(v.x), f2b(v.y), f2b(v.z), f2b(v.w)};
    *(ushort4*)&Wcat[(size_t)row * 256 + k4] = o;
}

// ---------------------------------------------------------------------------
// bf16 MFMA GEMM, v14: BM x 128 tile, 4 waves, pipelined staging.
// ACAST=1 (proj): A is f32 (raw state) — reg-staged with inline f32->bf16
//   cvt and a linear conflict-free ds_write_b128 (byte = 16*lane, identical
//   to the glds16 pattern). Loads for it+1 issue BEFORE compute(it); the
//   cvt+write land after (other buffer), preserving the async pipeline.
//   Deletes the state bf16 round-trip (16MB less HBM traffic + smaller cast).
// ACAST=0: A is bf16, glds16 direct (out GEMM).
// RELAYOUT=1 (proj): scatter C into head-major P planes.
// ---------------------------------------------------------------------------
template <int BF16OUT, int RELAYOUT, int BM, int ACAST>
__global__ __launch_bounds__(256) void gemm_mfma(const void* __restrict__ Av,
                                                 const ushort* __restrict__ Bw,
                                                 const float* __restrict__ bias,
                                                 void* __restrict__ Cv, int ldc) {
    constexpr int IR = BM / 32;  // 128 -> 4, 64 -> 2 (acc row-frags per wave)
    __shared__ __align__(16) ushort As[2][2][BM * 32];
    __shared__ __align__(16) ushort Bs[2][2][128 * 32];
    const int tid = threadIdx.x;
    const int lane = tid & 63;
    const int wave = tid >> 6;
    const int wm = (wave & 1) * (BM / 2);
    const int wn = (wave >> 1) * 64;
    const int row0 = blockIdx.x * BM;
    const int col0 = blockIdx.y * 128;

    const int lr = lane >> 2;        // 0..15
    const int lkq = (lane & 3) * 8;  // {0,8,16,24}

    const int arow = (BM == 128) ? (wave * 32) : (wave * 16);
    const ushort* gA0 = (const ushort*)Av + (size_t)(row0 + arow + lr) * 256 + lkq;
    const ushort* gA1 = gA0 + 16 * 256;  // BM==128 only
    const float* fA0 = (const float*)Av + (size_t)(row0 + arow + lr) * 256 + lkq;
    const float* fA1 = fA0 + 16 * 256;
    const ushort* gB0 = Bw + (size_t)(col0 + wave * 32 + lr) * 256 + lkq;
    const ushort* gB1 = gB0 + 16 * 256;

    const int fr = lane & 15;
    const int fk = (lane >> 4) * 8;

    f32x4 acc[IR][4] = {};
    float4 ald[2][2][2];  // ACAST: [panel][slab][half] in-flight A f32

    auto stageB = [&](int grp) {
        const int buf = grp & 1;
#pragma unroll
        for (int p = 0; p < 2; ++p) {
            const int ko = (grp * 2 + p) * 32;
            if (!ACAST) {
                glds16(gA0 + ko, &As[buf][p][arow * 32]);
                if (BM == 128) glds16(gA1 + ko, &As[buf][p][(arow + 16) * 32]);
            }
            glds16(gB0 + ko, &Bs[buf][p][(wave * 32) * 32]);
            glds16(gB1 + ko, &Bs[buf][p][(wave * 32 + 16) * 32]);
        }
    };
    auto loadA = [&](int grp) {
        if (!ACAST) return;
#pragma unroll
        for (int p = 0; p < 2; ++p) {
            const int ko = (grp * 2 + p) * 32;
            ald[p][0][0] = *(const float4*)(fA0 + ko);
            ald[p][0][1] = *(const float4*)(fA0 + ko + 4);
            ald[p][1][0] = *(const float4*)(fA1 + ko);
            ald[p][1][1] = *(const float4*)(fA1 + ko + 4);
        }
    };
    auto writeA = [&](int grp) {
        if (!ACAST) return;
        const int buf = grp & 1;
#pragma unroll
        for (int p = 0; p < 2; ++p)
#pragma unroll
            for (int s = 0; s < 2; ++s) {
                ushort o[8] __attribute__((aligned(16)));
                const float* f0 = (const float*)&ald[p][s][0];
                const float* f1 = (const float*)&ald[p][s][1];
#pragma unroll
                for (int q = 0; q < 4; ++q) {
                    o[q] = f2b(f0[q]);
                    o[4 + q] = f2b(f1[q]);
                }
                // byte offset = 16*lane within the 1KB slab: linear, conflict-free
                *(uint4*)&As[buf][p][(arow + s * 16 + lr) * 32 + lkq] = *(const uint4*)o;
            }
    };

    loadA(0);
    stageB(0);
    writeA(0);
    __syncthreads();  // drain prologue (vm + lgkm)

    for (int it = 0; it < 4; ++it) {
        if (it < 3) {
            loadA(it + 1);   // A f32 loads in flight during compute
            stageB(it + 1);  // B glds16 drains at loop barrier
        }
        const int buf = it & 1;
#pragma unroll
        for (int p = 0; p < 2; ++p) {
            bf16x8 af[IR], bf[4];
#pragma unroll
            for (int i = 0; i < IR; ++i)
                af[i] = *(const bf16x8*)&As[buf][p][(wm + i * 16 + fr) * 32 + fk];
#pragma unroll
            for (int j = 0; j < 4; ++j)
                bf[j] = *(const bf16x8*)&Bs[buf][p][(wn + j * 16 + fr) * 32 + fk];
#pragma unroll
            for (int i = 0; i < IR; ++i)
#pragma unroll
                for (int j = 0; j < 4; ++j)
                    acc[i][j] = __builtin_amdgcn_mfma_f32_16x16x32_bf16(af[i], bf[j], acc[i][j], 0, 0, 0);
        }
        if (it < 3) writeA(it + 1);  // cvt+write to buf^1 (not in use)
        __syncthreads();             // drain stage(it+1); protect buf reuse
    }

#pragma unroll
    for (int j = 0; j < 4; ++j) {
        const int col = col0 + wn + j * 16 + (lane & 15);
        const float bv = bias[col];
#pragma unroll
        for (int i = 0; i < IR; ++i) {
            const int rbase = row0 + wm + i * 16 + (lane >> 4) * 4;
#pragma unroll
            for (int r = 0; r < 4; ++r) {
                float o = acc[i][j][r] + bv;
                if (RELAYOUT) {
                    const int row = rbase + r;
                    const int bb = row >> 12, rr = row & 4095;
                    const int proj = col >> 8, hh = (col >> 5) & 7, dk = col & 31;
                    ((ushort*)Cv)[(size_t)proj * PROJ_ELEMS +
                                  ((size_t)(bb * 8 + hh) * 4096 + rr) * 32 + dk] = f2b(o);
                } else if (BF16OUT) {
                    ((ushort*)Cv)[(size_t)(rbase + r) * ldc + col] = f2b(o);
                } else {
                    ((float*)Cv)[(size_t)(rbase + r) * ldc + col] = o;
                }
            }
        }
    }
}

// ---------------------------------------------------------------------------
// FUSED scores + online-softmax + gated combine, v13 (unchanged from r9;
// measured 122.3 — equal to v11/v12 within noise; attn is at its practical
// floor for this decomposition).
// ---------------------------------------------------------------------------
__global__ __launch_bounds__(1024, 1) void fused_attn(const ushort* __restrict__ P,
                                                      const unsigned char* __restrict__ mask,
                                                      ushort* __restrict__ xbuf) {
    // LKb/LVb: [x16][a16][dk32] rows padded to 520; RVb: [y16][a16][dk32] pad 520;
    // RKb: [a16][y16][dk32] unpadded. atts: f32 [(a*16+y)][20] (x in row).
    __shared__ __align__(16) ushort LKb[2][16 * 520];
    __shared__ __align__(16) ushort LVb[2][16 * 520];
    __shared__ __align__(16) ushort RVb[2][16 * 520];
    __shared__ __align__(16) ushort RKb[2][16 * 512];
    __shared__ __align__(16) float atts[16 * 16 * 20];
    __shared__ float mstate[16 * 20];
    __shared__ float alphas[16 * 20];

    const int bh = blockIdx.z;
    const int b = bh >> 3, h = bh & 7;
    const int x0 = blockIdx.x * 16, y0 = blockIdx.y * 16;
    const int tid = threadIdx.x;
    const int lane = tid & 63, wave = tid >> 6;   // 16 waves

    const size_t HB = (size_t)bh * 4096 * 32;   // head slice offset (elements)
    const ushort* PLK = P + HB;
    const ushort* PRK = P + (size_t)1 * PROJ_ELEMS + HB;
    const ushort* PLV = P + (size_t)2 * PROJ_ELEMS + HB;
    const ushort* PRV = P + (size_t)3 * PROJ_ELEMS + HB;

    // scores coords (wave = a within chunk)
    const int fr = lane & 15, fk = (lane >> 4) * 8;
    const int yq = lane & 15, xq = (lane >> 4) * 4;
    // gate coords: wave = (xg, du); lane = (xi, gy). x = xg*4+xi.
    const int xg = wave >> 2, du = wave & 3;
    const int xi = lane >> 4, gy = lane & 15;
    const int gx = xg * 4 + xi;
    // softmax coords (threads 0..255): thread owns (x=sx, y=sy)
    const int sx = tid >> 4, sy = tid & 15;
    if (tid < 256) mstate[sx * 20 + sy] = -3.0e38f;

    // staging: wave -> plane (wave>>2), 4 rows (wave&3)*4..+3.
    const int splane = wave >> 2, srow0 = (wave & 3) * 4;
    const int sa = lane >> 2, soct = lane & 3;

    f32x2 acc[4] = {};
    float lacc = 0.0f;
    const float scale = 0.17677669529663687f; // 1/sqrt(32)

    unsigned char mreg[4];

#define STAGE(ac_, buf_)                                                                      \
    do {                                                                                      \
        _Pragma("unroll") for (int rr4 = 0; rr4 < 4; ++rr4) {                                 \
            const int row = srow0 + rr4;                                                      \
            if (splane == 0)                                                                  \
                glds16(PLK + ((size_t)(x0 + row) * 64 + (ac_) + sa) * 32 + soct * 8,          \
                       &LKb[buf_][row * 520]);                                                \
            else if (splane == 1)                                                             \
                glds16(PLV + ((size_t)(x0 + row) * 64 + (ac_) + sa) * 32 + soct * 8,          \
                       &LVb[buf_][row * 520]);                                                \
            else if (splane == 2)                                                             \
                glds16(PRV + ((size_t)((ac_) + sa) * 64 + y0 + row) * 32 + soct * 8,          \
                       &RVb[buf_][row * 520]);                                                \
            else                                                                              \
                glds16(PRK + ((size_t)((ac_) + row) * 64 + y0 + sa) * 32 + soct * 8,          \
                       &RKb[buf_][row * 512]);                                                \
        }                                                                                     \
    } while (0)

#define MLOAD(ac_)                                                                            \
    do {                                                                                      \
        _Pragma("unroll") for (int rr = 0; rr < 4; ++rr)                                      \
            mreg[rr] = mask[((size_t)(b * N + x0 + xq + rr) * N + (ac_) + wave) * N +         \
                            y0 + yq];                                                         \
    } while (0)

    // prologue: chunk 0 in flight; drained at first chunk-top barrier
    STAGE(0, 0);
    MLOAD(0);

    for (int c = 0; c < 4; ++c) {
        const int cur = c & 1;
        __syncthreads();  // drains STAGE(c)+MLOAD(c); all waves past gate(c-1)

        // ---- scores: 1 MFMA per wave (a = wave), frags from LDS ----
        {
            bf16x8 af = *(const bf16x8*)&LKb[cur][fr * 520 + wave * 32 + fk];
            bf16x8 bf = *(const bf16x8*)&RKb[cur][wave * 512 + fr * 32 + fk];
            f32x4 s = {};
            s = __builtin_amdgcn_mfma_f32_16x16x32_bf16(af, bf, s, 0, 0, 0);
            float4 ov;
            float* op = (float*)&ov;
#pragma unroll
            for (int rr = 0; rr < 4; ++rr) {
                float sv = s[rr] * scale;
                if (mreg[rr]) sv = -1000.0f;
                op[rr] = sv;
            }
            *(float4*)&atts[(wave * 16 + yq) * 20 + xq] = ov;  // [a][y][x], 1 b128
        }
        __syncthreads();  // atts visible

        // ---- online max over 16-a chunk: max + alpha only ----
        if (tid < 256) {
            float mc = -3.0e38f;
#pragma unroll
            for (int a = 0; a < 16; ++a) mc = fmaxf(mc, atts[(a * 16 + sy) * 20 + sx]);
            const float mold = mstate[sx * 20 + sy];
            const float mnew = fmaxf(mold, mc);
            mstate[sx * 20 + sy] = mnew;
            alphas[sx * 20 + sy] = __expf(mold - mnew);
        }
        __syncthreads();  // alphas/mstate visible

        // ---- issue next chunk's staging + mask (hides under the gate) ----
        if (c < 3) {
            STAGE((c + 1) * 16, cur ^ 1);
            MLOAD((c + 1) * 16);
        }

        // ---- rescale (acc and running l in regs) ----
        {
            const float av = alphas[gx * 20 + gy];
            lacc *= av;
#pragma unroll
            for (int q = 0; q < 4; ++q) acc[q] *= av;
        }
        const float mnv = mstate[gx * 20 + gy];

        // ---- gate: per a: rv 16-granule (2-way), lv 4-granule bcast,
        //      atts b32 (2-way); 1 exp; 8 pk-fma ----
        {
            const unsigned* LV32 = (const unsigned*)&LVb[cur][0];
            const unsigned* RV32 = (const unsigned*)&RVb[cur][0];
#pragma unroll
            for (int a = 0; a < 16; ++a) {
                const uint4 lvw = *(const uint4*)&LV32[gx * 260 + a * 16 + du * 4];
                const uint4 rvw = *(const uint4*)&RV32[gy * 260 + a * 16 + du * 4];
                const float w = __expf(atts[(a * 16 + gy) * 20 + gx] - mnv);
                lacc += w;
                acc[0] += (up2(lvw.x) * w) * up2(rvw.x);
                acc[1] += (up2(lvw.y) * w) * up2(rvw.y);
                acc[2] += (up2(lvw.z) * w) * up2(rvw.z);
                acc[3] += (up2(lvw.w) * w) * up2(rvw.w);
            }
        }
    }

    // ---- epilogue: divide by l (regs), one 16B store per thread ----
    {
        const float il = 1.0f / lacc;
        ushort o[8] __attribute__((aligned(16)));
#pragma unroll
        for (int q = 0; q < 4; ++q) {
            o[2 * q]     = f2b(acc[q].x * il);
            o[2 * q + 1] = f2b(acc[q].y * il);
        }
        *(uint4*)&xbuf[(((size_t)b * N + x0 + gx) * N + y0 + gy) * D + h * DK + du * 8] =
            *(const uint4*)o;
    }
#undef STAGE
#undef MLOAD
}

// ---------------------------------------------------------------------------
extern "C" void kernel_launch(void* const* d_in, const int* in_sizes, int n_in,
                              void* d_out, int out_size, void* d_ws, size_t ws_size,
                              hipStream_t stream) {
    const float* state = (const float*)d_in[0];
    const unsigned char* mask = (const unsigned char*)d_in[1];
    const float* W_lk = (const float*)d_in[2];
    const float* b_lk = (const float*)d_in[3];
    const float* W_rk = (const float*)d_in[4];
    const float* b_rk = (const float*)d_in[5];
    const float* W_lv = (const float*)d_in[6];
    const float* b_lv = (const float*)d_in[7];
    const float* W_rv = (const float*)d_in[8];
    const float* b_rv = (const float*)d_in[9];
    const float* W_o = (const float*)d_in[10];
    const float* b_o = (const float*)d_in[11];
    float* out = (float*)d_out;

    char* ws = (char*)d_ws;
    ushort* P_bf = (ushort*)ws;                          // 4 proj planes, 16.8 MB
    ws += (size_t)4 * PROJ_ELEMS * 2;
    float* bias_cat = (float*)ws;                        // 1280 f32
    ws += 1280 * 4;
    ushort* Wcat = (ushort*)ws;                          // 0.65 MB
    ws += (size_t)1280 * 256 * 2;
    ushort* xbuf_bf = (ushort*)ws;                       // 4 MB

    cast_w<<<320, 256, 0, stream>>>(W_lk, W_rk, W_lv, W_rv, W_o,
                                    b_lk, b_rk, b_lv, b_rv, b_o,
                                    Wcat, bias_cat);
    gemm_mfma<1, 1, 128, 1><<<dim3(M / 128, 8), 256, 0, stream>>>(state, Wcat, bias_cat, P_bf, 1024);
    fused_attn<<<dim3(4, 4, B * H), 1024, 0, stream>>>(P_bf, mask, xbuf_bf);
    gemm_mfma<0, 0, 64, 0><<<dim3(M / 64, 2), 256, 0, stream>>>(xbuf_bf, Wcat + 1024 * 256, bias_cat + 1024, out, 256);
}